// Round 6
// baseline (54.586 us; speedup 1.0000x reference)
//
#include <hip/hip_runtime.h>
#include <hip/hip_fp16.h>

// InnerProductDecoder: out[e] = sigmoid( dot(z[row[e]], z[col[e]]) ), D=64.
// fp16-compacted z in d_ws (128 B/node = one cache line), 8 lanes/edge gather.
// This round: nontemporal (nt) loads/stores for the STREAMED data (edge index,
// output, cvt-pass z reads) so they don't evict zh lines from the 4 MiB/XCD L2.
// zh gathers stay normally-cached (they ARE the reuse).

typedef float f32x4 __attribute__((ext_vector_type(4)));
typedef unsigned int u32x4 __attribute__((ext_vector_type(4)));

__global__ __launch_bounds__(256) void cvt_f32_to_f16(const float* __restrict__ z,
                                                      __half* __restrict__ zh,
                                                      int n4) {
    int i = blockIdx.x * blockDim.x + threadIdx.x;
    if (i >= n4) return;
    const f32x4 v = __builtin_nontemporal_load(reinterpret_cast<const f32x4*>(z) + i);
    __half2 h0 = __floats2half2_rn(v.x, v.y);
    __half2 h1 = __floats2half2_rn(v.z, v.w);
    uint2 packed;
    packed.x = *reinterpret_cast<unsigned int*>(&h0);
    packed.y = *reinterpret_cast<unsigned int*>(&h1);
    reinterpret_cast<uint2*>(zh)[i] = packed;   // normal store: may seed L2 with zh
}

__global__ __launch_bounds__(256) void ipd_f16_kernel(const __half* __restrict__ zh,
                                                      const int* __restrict__ ei,
                                                      float* __restrict__ out,
                                                      int E) {
    const long long gid = (long long)blockIdx.x * blockDim.x + threadIdx.x;
    const long long edge = gid >> 3;     // 8 lanes per edge
    const int lane = (int)(gid & 7);
    if (edge >= E) return;

    // Streamed index reads: nontemporal (same addr across the 8-lane group -> broadcast).
    const int r = __builtin_nontemporal_load(ei + edge);
    const int c = __builtin_nontemporal_load(ei + E + edge);

    const u32x4 av = *reinterpret_cast<const u32x4*>(zh + (size_t)r * 64 + lane * 8);
    const u32x4 bv = *reinterpret_cast<const u32x4*>(zh + (size_t)c * 64 + lane * 8);

    float s = 0.0f;
#pragma unroll
    for (int i = 0; i < 4; ++i) {
        const unsigned int aw = av[i];
        const unsigned int bw = bv[i];
        const __half2 ha = __builtin_bit_cast(__half2, aw);
        const __half2 hb = __builtin_bit_cast(__half2, bw);
        float2 fa = __half22float2(ha);
        float2 fb = __half22float2(hb);
        s += fa.x * fb.x + fa.y * fb.y;
    }

    // Butterfly reduce across the 8-lane group.
    s += __shfl_xor(s, 4, 8);
    s += __shfl_xor(s, 2, 8);
    s += __shfl_xor(s, 1, 8);

    if (lane == 0) {
        const float v = __builtin_amdgcn_rcpf(1.0f + __expf(-s));
        __builtin_nontemporal_store(v, out + edge);   // streamed output, no reuse
    }
}

// Fallback (fp32 gathers) if workspace is too small for the fp16 copy of z.
__global__ __launch_bounds__(256) void ipd_f32_kernel(const float* __restrict__ z,
                                                      const int* __restrict__ ei,
                                                      float* __restrict__ out,
                                                      int E) {
    const long long gid = (long long)blockIdx.x * blockDim.x + threadIdx.x;
    const long long edge = gid >> 4;
    const int lane = (int)(gid & 15);
    if (edge >= E) return;
    const int r = ei[edge];
    const int c = ei[E + edge];
    const float4 a = *reinterpret_cast<const float4*>(z + (size_t)r * 64 + lane * 4);
    const float4 b = *reinterpret_cast<const float4*>(z + (size_t)c * 64 + lane * 4);
    float s = a.x * b.x + a.y * b.y + a.z * b.z + a.w * b.w;
    s += __shfl_xor(s, 8, 16);
    s += __shfl_xor(s, 4, 16);
    s += __shfl_xor(s, 2, 16);
    s += __shfl_xor(s, 1, 16);
    if (lane == 0) out[edge] = __builtin_amdgcn_rcpf(1.0f + __expf(-s));
}

extern "C" void kernel_launch(void* const* d_in, const int* in_sizes, int n_in,
                              void* d_out, int out_size, void* d_ws, size_t ws_size,
                              hipStream_t stream) {
    const float* z = (const float*)d_in[0];
    const int* ei = (const int*)d_in[1];
    float* out = (float*)d_out;

    const int nz = in_sizes[0];       // N_NODES * 64 floats
    const int E = in_sizes[1] / 2;    // edge_index is [2, E]
    const size_t zh_bytes = (size_t)nz * sizeof(__half);

    if (ws_size >= zh_bytes) {
        __half* zh = (__half*)d_ws;
        const int n4 = nz / 4;
        cvt_f32_to_f16<<<(n4 + 255) / 256, 256, 0, stream>>>(z, zh, n4);

        const long long total = (long long)E * 8;
        ipd_f16_kernel<<<(int)((total + 255) / 256), 256, 0, stream>>>(zh, ei, out, E);
    } else {
        const long long total = (long long)E * 16;
        ipd_f32_kernel<<<(int)((total + 255) / 256), 256, 0, stream>>>(z, ei, out, E);
    }
}

// Round 7
// 48.582 us; speedup vs baseline: 1.1236x; 1.1236x over previous
//
#include <hip/hip_runtime.h>
#include <hip/hip_fp16.h>

// InnerProductDecoder: out[e] = sigmoid( dot(z[row[e]], z[col[e]]) ), D=64.
// Final structure (Round-4 revert): convert z -> fp16 in d_ws (one streaming
// pass), so each node is 128 B = exactly one cache line; then 8 lanes/edge
// gather both nodes (8 x 16 B coalesced per node), fp32 dot, 3-step shuffle
// reduce, sigmoid on lane 0.
// Round-6 lesson: do NOT nt-hint the index/output streams — index lines are
// reused by ~4 consecutive waves and output stores rely on L2 write-combining;
// nt inflated miss-path traffic (+13%).

__global__ __launch_bounds__(256) void cvt_f32_to_f16(const float* __restrict__ z,
                                                      __half* __restrict__ zh,
                                                      int n4) {
    int i = blockIdx.x * blockDim.x + threadIdx.x;
    if (i >= n4) return;
    const float4 v = reinterpret_cast<const float4*>(z)[i];
    __half2 h0 = __floats2half2_rn(v.x, v.y);
    __half2 h1 = __floats2half2_rn(v.z, v.w);
    uint2 packed;
    packed.x = *reinterpret_cast<unsigned int*>(&h0);
    packed.y = *reinterpret_cast<unsigned int*>(&h1);
    reinterpret_cast<uint2*>(zh)[i] = packed;
}

__global__ __launch_bounds__(256) void ipd_f16_kernel(const __half* __restrict__ zh,
                                                      const int* __restrict__ ei,
                                                      float* __restrict__ out,
                                                      int E) {
    const long long gid = (long long)blockIdx.x * blockDim.x + threadIdx.x;
    const long long edge = gid >> 3;     // 8 lanes per edge
    const int lane = (int)(gid & 7);
    if (edge >= E) return;

    const int r = ei[edge];       // broadcast within 8-lane group
    const int c = ei[E + edge];

    const uint4 av = *reinterpret_cast<const uint4*>(zh + (size_t)r * 64 + lane * 8);
    const uint4 bv = *reinterpret_cast<const uint4*>(zh + (size_t)c * 64 + lane * 8);

    const __half2* ah = reinterpret_cast<const __half2*>(&av);
    const __half2* bh = reinterpret_cast<const __half2*>(&bv);

    float s = 0.0f;
#pragma unroll
    for (int i = 0; i < 4; ++i) {
        float2 fa = __half22float2(ah[i]);
        float2 fb = __half22float2(bh[i]);
        s += fa.x * fb.x + fa.y * fb.y;
    }

    // Butterfly reduce across the 8-lane group.
    s += __shfl_xor(s, 4, 8);
    s += __shfl_xor(s, 2, 8);
    s += __shfl_xor(s, 1, 8);

    if (lane == 0) {
        out[edge] = __builtin_amdgcn_rcpf(1.0f + __expf(-s));
    }
}

// Fallback (fp32 gathers) if workspace is too small for the fp16 copy of z.
__global__ __launch_bounds__(256) void ipd_f32_kernel(const float* __restrict__ z,
                                                      const int* __restrict__ ei,
                                                      float* __restrict__ out,
                                                      int E) {
    const long long gid = (long long)blockIdx.x * blockDim.x + threadIdx.x;
    const long long edge = gid >> 4;
    const int lane = (int)(gid & 15);
    if (edge >= E) return;
    const int r = ei[edge];
    const int c = ei[E + edge];
    const float4 a = *reinterpret_cast<const float4*>(z + (size_t)r * 64 + lane * 4);
    const float4 b = *reinterpret_cast<const float4*>(z + (size_t)c * 64 + lane * 4);
    float s = a.x * b.x + a.y * b.y + a.z * b.z + a.w * b.w;
    s += __shfl_xor(s, 8, 16);
    s += __shfl_xor(s, 4, 16);
    s += __shfl_xor(s, 2, 16);
    s += __shfl_xor(s, 1, 16);
    if (lane == 0) out[edge] = __builtin_amdgcn_rcpf(1.0f + __expf(-s));
}

extern "C" void kernel_launch(void* const* d_in, const int* in_sizes, int n_in,
                              void* d_out, int out_size, void* d_ws, size_t ws_size,
                              hipStream_t stream) {
    const float* z = (const float*)d_in[0];
    const int* ei = (const int*)d_in[1];
    float* out = (float*)d_out;

    const int nz = in_sizes[0];       // N_NODES * 64 floats
    const int E = in_sizes[1] / 2;    // edge_index is [2, E]
    const size_t zh_bytes = (size_t)nz * sizeof(__half);

    if (ws_size >= zh_bytes) {
        __half* zh = (__half*)d_ws;
        const int n4 = nz / 4;
        cvt_f32_to_f16<<<(n4 + 255) / 256, 256, 0, stream>>>(z, zh, n4);

        const long long total = (long long)E * 8;
        ipd_f16_kernel<<<(int)((total + 255) / 256), 256, 0, stream>>>(zh, ei, out, E);
    } else {
        const long long total = (long long)E * 16;
        ipd_f32_kernel<<<(int)((total + 255) / 256), 256, 0, stream>>>(z, ei, out, E);
    }
}